// Round 10
// baseline (354.015 us; speedup 1.0000x reference)
//
#include <hip/hip_runtime.h>

// ShootingBlockMNModel1 — single fused kernel, regular launch (graph-safe).
// FLAT ALL-GATHER: no reducer, no broadcast. Every block:
//   accumulate -> store 36 f32 partials (double-buffered by k&1) ->
//   syncthreads (drains vmcnt) -> release arr[bid]=k+1 ->
//   wave0 polls 256 arrival epochs (4/lane, 1KB, sleep backoff) ->
//   all waves gather 36x256 partials (20 f32/lane, coalesced, IC-resident) ->
//   12-thread grad -> next iter. Theta/backfold computed REDUNDANTLY per
//   block (bit-identical: same reduction order) -> final phase fully local.
// Double-buffer safety is PROTOCOL-guaranteed: arr[B]>=k+1 implies B finished
// its (k-1) gather, so overwriting buf[(k-1)&1] at iter k+1 cannot race.
// 256 blocks, __launch_bounds__(512,2): the proven 1-block/CU config (r8's
// 257-block failure = non-resident block -> watchdog; never exceed capacity).
//
// ws: part32[2][36][NB] f32 (no init needed) ; arr[NB] u32 (memset 1KB)

#define LR 0.25f
#define NIT 20
#define TPB 512
#define NB  256
#define GUARD (1<<20)

typedef float v2f __attribute__((ext_vector_type(2)));

#define AG_LDF(p)  __hip_atomic_load((p),  __ATOMIC_RELAXED, __HIP_MEMORY_SCOPE_AGENT)
#define AG_STF(p,v) __hip_atomic_store((p), (v), __ATOMIC_RELAXED, __HIP_MEMORY_SCOPE_AGENT)
#define AG_LDU(p)  __hip_atomic_load((p),  __ATOMIC_RELAXED, __HIP_MEMORY_SCOPE_AGENT)

__device__ __forceinline__ v2f tanh2(v2f x){
    v2f e;
    e.x = __expf(x.x + x.x);
    e.y = __expf(x.y + x.y);
    v2f d = e + 1.0f;
    v2f r;
    r.x = __builtin_amdgcn_rcpf(d.x);
    r.y = __builtin_amdgcn_rcpf(d.y);
    return 1.0f - (r + r);
}

// wave64 sum via DPP on the VALU pipe; result valid in lane 63
#define DPP_ADD(x, ctrl) ((x) + __int_as_float(__builtin_amdgcn_update_dpp(0, __float_as_int(x), (ctrl), 0xF, 0xF, true)))
__device__ __forceinline__ float wave_sum64(float x){
    x = DPP_ADD(x, 0x111);   // row_shr:1
    x = DPP_ADD(x, 0x112);   // row_shr:2
    x = DPP_ADD(x, 0x114);   // row_shr:4
    x = DPP_ADD(x, 0x118);   // row_shr:8  -> lane 15+16r = row sum
    x = DPP_ADD(x, 0x142);   // row_bcast:15
    x = DPP_ADD(x, 0x143);   // row_bcast:31 -> lane 63 = total
    return x;
}

__device__ __forceinline__ void compute_grad(const float* s, const float* th,
                                             const float* ksym, const float* ksymb,
                                             float c, float* g){
    const float Ivec[4]={1.f,0.f,0.f,1.f};
    #pragma unroll
    for(int j=0;j<4;j++){
        float kv=0.f;
        #pragma unroll
        for(int m=0;m<4;m++) kv += ksym[j*4+m]*th[m];
        g[j] = kv - c*s[j];
    }
    #pragma unroll
    for(int i2=0;i2<2;i2++)
        g[4+i2] = ksymb[i2*2+0]*th[4] + ksymb[i2*2+1]*th[5] - c*s[4+i2];
    #pragma unroll
    for(int j=0;j<4;j++){
        float kv=0.f;
        #pragma unroll
        for(int m=0;m<4;m++) kv += ksym[j*4+m]*(th[6+m]-Ivec[m]);
        g[6+j] = kv - c*s[6+j];
    }
    #pragma unroll
    for(int i2=0;i2<2;i2++)
        g[10+i2] = ksymb[i2*2+0]*th[10] + ksymb[i2*2+1]*th[11] - c*s[10+i2];
}

// packed accumulate: float4 = 2 samples in v2f lanes
__device__ __forceinline__ void accum_sample2(v2f Q0, v2f Q1, v2f P0, v2f P1,
    float t1_00,float t1_01,float t1_10,float t1_11,
    float t2_00,float t2_01,float t2_10,float t2_11,float b2_0,float b2_1,
    v2f (&acc)[36]){
    v2f u0 = t2_00*Q0 + t2_01*Q1 + b2_0;
    v2f u1 = t2_10*Q0 + t2_11*Q1 + b2_1;
    v2f h0 = tanh2(u0), h1 = tanh2(u1);
    v2f s0 = 1.0f - h0*h0, s1 = 1.0f - h1*h1;
    v2f a0 = t1_00*P0 + t1_10*P1;
    v2f a1 = t1_01*P0 + t1_11*P1;
    v2f w0 = a0*s0, w1 = a1*s1;
    v2f r0 = -2.0f*(a0*h0)*s0, r1 = -2.0f*(a1*h1)*s1;
    acc[0]+=P0*h0; acc[1]+=P0*h1; acc[2]+=P1*h0; acc[3]+=P1*h1;
    acc[4]+=P0;    acc[5]+=P1;
    acc[6]+=w0*Q0; acc[7]+=w0*Q1; acc[8]+=w1*Q0; acc[9]+=w1*Q1;
    acc[10]+=w0;   acc[11]+=w1;
    v2f ps00=P0*s0, ps01=P0*s1, ps10=P1*s0, ps11=P1*s1;
    acc[12]+=ps00*Q0; acc[13]+=ps00*Q1; acc[14]+=ps01*Q0; acc[15]+=ps01*Q1;
    acc[16]+=ps10*Q0; acc[17]+=ps10*Q1; acc[18]+=ps11*Q0; acc[19]+=ps11*Q1;
    acc[20]+=ps00; acc[21]+=ps01; acc[22]+=ps10; acc[23]+=ps11;
    v2f r0q0=r0*Q0, r1q0=r1*Q0;
    acc[24]+=r0q0*Q0; acc[25]+=r0q0*Q1; acc[26]+=r0*(Q1*Q1);
    acc[27]+=r1q0*Q0; acc[28]+=r1q0*Q1; acc[29]+=r1*(Q1*Q1);
    acc[30]+=r0q0; acc[31]+=r0*Q1; acc[32]+=r1q0; acc[33]+=r1*Q1;
    acc[34]+=r0; acc[35]+=r1;
}

__device__ __forceinline__ void bk_step2(v2f Q0, v2f Q1, v2f P0, v2f P1,
    float t1_00,float t1_01,float t1_10,float t1_11,
    float t2_00,float t2_01,float t2_10,float t2_11,float b2_0,float b2_1,
    float L1_00,float L1_01,float L1_10,float L1_11,
    float L2_00,float L2_01,float L2_10,float L2_11,float lb2_0,float lb2_1,
    v2f &B0, v2f &B1){
    v2f u0 = t2_00*Q0 + t2_01*Q1 + b2_0;
    v2f u1 = t2_10*Q0 + t2_11*Q1 + b2_1;
    v2f h0 = tanh2(u0), h1 = tanh2(u1);
    v2f s0 = 1.0f - h0*h0, s1 = 1.0f - h1*h1;
    v2f a0 = t1_00*P0 + t1_10*P1;
    v2f a1 = t1_01*P0 + t1_11*P1;
    v2f w0 = a0*s0, w1 = a1*s1;
    v2f r0 = -2.0f*(a0*h0)*s0, r1 = -2.0f*(a1*h1)*s1;
    v2f lp0 = L1_00*P0 + L1_10*P1;
    v2f lp1 = L1_01*P0 + L1_11*P1;
    v2f z0 = L2_00*Q0 + L2_01*Q1 + lb2_0;
    v2f z1 = L2_10*Q0 + L2_11*Q1 + lb2_1;
    v2f m0 = lp0*s0 + r0*z0;
    v2f m1 = lp1*s1 + r1*z1;
    B0 += t2_00*m0 + t2_10*m1 + L2_00*w0 + L2_10*w1;
    B1 += t2_01*m0 + t2_11*m1 + L2_01*w0 + L2_11*w1;
}

__global__ __launch_bounds__(TPB, 2) void k_all(
    const float4* __restrict__ q4, const float4* __restrict__ p4,
    const float4* __restrict__ x4, int nv4,
    const float* __restrict__ t1i, const float* __restrict__ b1i,
    const float* __restrict__ t2i, const float* __restrict__ b2i,
    const float* __restrict__ invK, const float* __restrict__ invKb,
    float* __restrict__ part32,          // [2][36][NB] partials (dbuf by k&1)
    unsigned* __restrict__ arr,          // [NB] arrival epochs, zeroed
    float4* __restrict__ oq, float4* __restrict__ op, float4* __restrict__ ox,
    float c)
{
    const int tid  = threadIdx.x;
    const int bid  = blockIdx.x;
    const int NT   = gridDim.x * TPB;
    const int gtid = bid*TPB + tid;
    const int wave = tid >> 6, lane = tid & 63;

    __shared__ float ths[12];                  // current theta (ends as theta20)
    __shared__ float thetaAll[(NIT+1)*12];     // every block
    __shared__ float sAll[(NIT+1)*36];         // every block
    __shared__ float red[TPB/64][36];
    __shared__ float ks[16], ksb[4];
    __shared__ float4 pkS[NIT*5];              // packed theta_k + lam_{k+1}

    if(tid < 16) ks[tid]  = 0.5f*(invK[tid]  + invK[(tid&3)*4 + (tid>>2)]);
    if(tid < 4)  ksb[tid] = 0.5f*(invKb[tid] + invKb[(tid&1)*2 + (tid>>1)]);
    if(tid < 12){
        float v = (tid<4)? t1i[tid] : (tid<6)? b1i[tid-4]
                : (tid<10)? t2i[tid-6] : b2i[tid-10];
        ths[tid] = v;
        thetaAll[tid] = v;
    }
    __syncthreads();

    // Pin this thread's samples in registers for the whole kernel.
    const bool fast = (nv4 == 4*NT);
    float4 qd[4], pd[4];
    if(fast){
        #pragma unroll
        for(int sl=0; sl<4; sl++){ qd[sl]=q4[gtid + sl*NT]; pd[sl]=p4[gtid + sl*NT]; }
    }

    for(int k=0; k<=NIT; k++){
        const float t1_00=ths[0], t1_01=ths[1], t1_10=ths[2], t1_11=ths[3];
        const float t2_00=ths[6], t2_01=ths[7], t2_10=ths[8], t2_11=ths[9];
        const float b2_0=ths[10], b2_1=ths[11];

        v2f acc[36];
        #pragma unroll
        for(int j=0;j<36;j++) acc[j] = (v2f){0.f, 0.f};

        if(fast){
            #pragma unroll
            for(int sl=0; sl<4; sl++){
                v2f Q0={qd[sl].x,qd[sl].z}, Q1={qd[sl].y,qd[sl].w};
                v2f P0={pd[sl].x,pd[sl].z}, P1={pd[sl].y,pd[sl].w};
                accum_sample2(Q0,Q1,P0,P1,
                    t1_00,t1_01,t1_10,t1_11,t2_00,t2_01,t2_10,t2_11,b2_0,b2_1,acc);
            }
        }else{
            for(int j = gtid; j < nv4; j += NT){
                float4 qq = q4[j], pp = p4[j];
                v2f Q0={qq.x,qq.z}, Q1={qq.y,qq.w};
                v2f P0={pp.x,pp.z}, P1={pp.y,pp.w};
                accum_sample2(Q0,Q1,P0,P1,
                    t1_00,t1_01,t1_10,t1_11,t2_00,t2_01,t2_10,t2_11,b2_0,b2_1,acc);
            }
        }

        // wave reduction (VALU pipe) -> block partials -> dbuf store
        float wres[36];
        #pragma unroll
        for(int j=0;j<36;j++) wres[j] = wave_sum64(acc[j].x + acc[j].y);
        if(lane == 63){
            #pragma unroll
            for(int j=0;j<36;j++) red[wave][j] = wres[j];
        }
        __syncthreads();
        float* buf = part32 + (size_t)(k & 1)*36*NB;
        if(tid < 36){
            float sum = 0.f;
            #pragma unroll
            for(int w=0; w<TPB/64; w++) sum += red[w][tid];
            AG_STF(buf + tid*NB + bid, sum);
        }
        __syncthreads();   // drains vmcnt for all waves -> partials visible
        if(tid == 0)
            __hip_atomic_store(arr + bid, (unsigned)(k+1),
                               __ATOMIC_RELEASE, __HIP_MEMORY_SCOPE_AGENT);

        // detect: wave0 polls 256 arrival epochs (4/lane, 1KB region)
        if(wave == 0){
            const unsigned tgt = (unsigned)(k+1);
            const unsigned* a = arr + lane*4;
            int guard = 0;
            for(;;){
                unsigned f0=AG_LDU(a+0), f1=AG_LDU(a+1), f2=AG_LDU(a+2), f3=AG_LDU(a+3);
                if(__all(f0>=tgt && f1>=tgt && f2>=tgt && f3>=tgt)) break;
                __builtin_amdgcn_s_sleep(2);
                if(++guard > GUARD) break;   // watchdog: wrong-answer, never hang
            }
        }
        __syncthreads();

        // gather: every wave, rows {w, w+8, w+16, w+24}(+w+32 if w<4),
        // cols {lane, lane+64, lane+128, lane+192} — coalesced f32, 1 round trip
        {
            const int r4i = (wave<4)? (wave+32) : (wave+24); // dummy repeat if wave>=4
            const float* R0 = buf + (size_t)(wave     )*NB;
            const float* R1 = buf + (size_t)(wave +  8)*NB;
            const float* R2 = buf + (size_t)(wave + 16)*NB;
            const float* R3 = buf + (size_t)(wave + 24)*NB;
            const float* R4 = buf + (size_t)(r4i      )*NB;
            float a0=AG_LDF(R0+lane), a1=AG_LDF(R0+lane+64), a2=AG_LDF(R0+lane+128), a3=AG_LDF(R0+lane+192);
            float b0=AG_LDF(R1+lane), b1=AG_LDF(R1+lane+64), b2=AG_LDF(R1+lane+128), b3=AG_LDF(R1+lane+192);
            float c0=AG_LDF(R2+lane), c1=AG_LDF(R2+lane+64), c2=AG_LDF(R2+lane+128), c3=AG_LDF(R2+lane+192);
            float d0=AG_LDF(R3+lane), d1=AG_LDF(R3+lane+64), d2=AG_LDF(R3+lane+128), d3=AG_LDF(R3+lane+192);
            float e0=AG_LDF(R4+lane), e1=AG_LDF(R4+lane+64), e2=AG_LDF(R4+lane+128), e3=AG_LDF(R4+lane+192);
            float s0 = wave_sum64(a0+a1+a2+a3);
            float s1 = wave_sum64(b0+b1+b2+b3);
            float s2 = wave_sum64(c0+c1+c2+c3);
            float s3 = wave_sum64(d0+d1+d2+d3);
            float s4 = wave_sum64(e0+e1+e2+e3);
            if(lane == 63){
                sAll[k*36 + wave]      = s0;
                sAll[k*36 + wave + 8]  = s1;
                sAll[k*36 + wave + 16] = s2;
                sAll[k*36 + wave + 24] = s3;
                if(wave < 4) sAll[k*36 + wave + 32] = s4;
            }
        }
        __syncthreads();

        // 12-thread parallel grad -> theta_{k+1} (bit-identical on all blocks)
        if(k < NIT){
            if(tid < 12){
                const float* th = thetaAll + k*12;
                const float* s  = sAll + k*36;
                float g;
                if(tid < 4){
                    float kv=0.f;
                    #pragma unroll
                    for(int m=0;m<4;m++) kv += ks[tid*4+m]*th[m];
                    g = kv - c*s[tid];
                }else if(tid < 6){
                    int i2 = tid-4;
                    g = ksb[i2*2+0]*th[4] + ksb[i2*2+1]*th[5] - c*s[tid];
                }else if(tid < 10){
                    int j = tid-6;
                    float kv=0.f;
                    #pragma unroll
                    for(int m=0;m<4;m++){
                        float Iv = (m==0 || m==3) ? 1.f : 0.f;
                        kv += ks[j*4+m]*(th[6+m]-Iv);
                    }
                    g = kv - c*s[tid];
                }else{
                    int i2 = tid-10;
                    g = ksb[i2*2+0]*th[10] + ksb[i2*2+1]*th[11] - c*s[tid];
                }
                float t = th[tid] - LR*g;
                ths[tid] = t;
                thetaAll[(k+1)*12+tid] = t;
            }
            __syncthreads();
        }
    }

    // ---- backfold: redundant per block, fully local (sAll/thetaAll in LDS) ----
    if(tid == 0){
        float lv[12];
        compute_grad(sAll + NIT*36, thetaAll + NIT*12, ks, ksb, c, lv);
        for(int k=NIT-1;k>=0;k--){
            const float* s = sAll + k*36;
            const float* T = thetaAll + k*12;
            float* P = (float*)&pkS[k*5];
            P[0]=T[0]; P[1]=T[1]; P[2]=T[2]; P[3]=T[3];
            P[4]=T[6]; P[5]=T[7]; P[6]=T[8]; P[7]=T[9];
            P[8]=T[10]; P[9]=T[11];
            P[10]=lv[0]; P[11]=lv[1]; P[12]=lv[2]; P[13]=lv[3];
            P[14]=lv[6]; P[15]=lv[7]; P[16]=lv[8]; P[17]=lv[9];
            P[18]=lv[10]; P[19]=lv[11];
            float H[12];
            for(int a=0;a<2;a++)for(int b=0;b<2;b++){
                int j=a*2+b;
                float data = s[12+a*4+b*2+0]*lv[6+b*2+0]
                           + s[12+a*4+b*2+1]*lv[6+b*2+1]
                           + s[20+a*2+b]*lv[10+b];
                float kv=0.f;
                for(int m=0;m<4;m++) kv += ks[j*4+m]*lv[m];
                H[j]=kv - c*data;
            }
            H[4] = ksb[0]*lv[4] + ksb[1]*lv[5];
            H[5] = ksb[2]*lv[4] + ksb[3]*lv[5];
            for(int cc=0;cc<2;cc++)for(int d=0;d<2;d++){
                int j=cc*2+d;
                float term1 = lv[0+cc]*s[12+0*4+cc*2+d] + lv[2+cc]*s[12+1*4+cc*2+d];
                float term2 = lv[6+cc*2+0]*s[24+cc*3+(0+d)] + lv[6+cc*2+1]*s[24+cc*3+(1+d)];
                float term3 = lv[10+cc]*s[30+cc*2+d];
                float kv=0.f;
                for(int m=0;m<4;m++) kv += ks[j*4+m]*lv[6+m];
                H[6+j]=kv - c*(term1+term2+term3);
            }
            for(int cc=0;cc<2;cc++){
                float z1 = lv[0+cc]*s[20+0*2+cc] + lv[2+cc]*s[20+1*2+cc];
                float z2 = lv[6+cc*2+0]*s[30+cc*2+0] + lv[6+cc*2+1]*s[30+cc*2+1];
                float z3 = lv[10+cc]*s[34+cc];
                float kv = ksb[cc*2+0]*lv[10] + ksb[cc*2+1]*lv[11];
                H[10+cc]=kv - c*(z1+z2+z3);
            }
            for(int j=0;j<12;j++) lv[j] -= LR*H[j];
        }
    }
    __syncthreads();

    // ---- final phase: fully local (ths == theta20, pkS in LDS) ----
    const float f1_00=ths[0], f1_01=ths[1], f1_10=ths[2], f1_11=ths[3];
    const float fb1_0=ths[4], fb1_1=ths[5];
    const float f2_00=ths[6], f2_01=ths[7], f2_10=ths[8], f2_11=ths[9];
    const float fb2_0=ths[10], fb2_1=ths[11];

    if(fast){
        #pragma unroll
        for(int sl=0; sl<4; sl++){
            int j = gtid + sl*NT;
            v2f Q0={qd[sl].x,qd[sl].z}, Q1={qd[sl].y,qd[sl].w};
            v2f u0 = f2_00*Q0 + f2_01*Q1 + fb2_0;
            v2f u1 = f2_10*Q0 + f2_11*Q1 + fb2_1;
            v2f h0 = tanh2(u0), h1 = tanh2(u1);
            v2f dq0 = f1_00*h0 + f1_01*h1 + fb1_0;
            v2f dq1 = f1_10*h0 + f1_11*h1 + fb1_1;
            oq[j] = make_float4(dq0.x, dq1.x, dq0.y, dq1.y);
            float4 xx = x4[j];
            v2f X0={xx.x,xx.z}, X1={xx.y,xx.w};
            v2f xu0 = f2_00*X0 + f2_01*X1 + fb2_0;
            v2f xu1 = f2_10*X0 + f2_11*X1 + fb2_1;
            v2f xh0 = tanh2(xu0), xh1 = tanh2(xu1);
            v2f xd0 = f1_00*xh0 + f1_01*xh1 + fb1_0;
            v2f xd1 = f1_10*xh0 + f1_11*xh1 + fb1_1;
            ox[j] = make_float4(xd0.x, xd1.x, xd0.y, xd1.y);
        }
        v2f B0r[4],B1r[4];
        #pragma unroll
        for(int sl=0; sl<4; sl++){ B0r[sl]=(v2f){0.f,0.f}; B1r[sl]=(v2f){0.f,0.f}; }
        for(int k=0;k<NIT;k++){
            float4 P0=pkS[k*5+0], P1=pkS[k*5+1], P2=pkS[k*5+2], P3=pkS[k*5+3], P4v=pkS[k*5+4];
            float t1_00=P0.x,t1_01=P0.y,t1_10=P0.z,t1_11=P0.w;
            float t2_00=P1.x,t2_01=P1.y,t2_10=P1.z,t2_11=P1.w;
            float b2_0=P2.x,b2_1=P2.y;
            float L1_00=P2.z,L1_01=P2.w,L1_10=P3.x,L1_11=P3.y;
            float L2_00=P3.z,L2_01=P3.w,L2_10=P4v.x,L2_11=P4v.y,lb2_0=P4v.z,lb2_1=P4v.w;
            #pragma unroll
            for(int sl=0; sl<4; sl++){
                v2f Q0={qd[sl].x,qd[sl].z}, Q1={qd[sl].y,qd[sl].w};
                v2f P0s={pd[sl].x,pd[sl].z}, P1s={pd[sl].y,pd[sl].w};
                bk_step2(Q0,Q1,P0s,P1s,
                    t1_00,t1_01,t1_10,t1_11,t2_00,t2_01,t2_10,t2_11,b2_0,b2_1,
                    L1_00,L1_01,L1_10,L1_11,L2_00,L2_01,L2_10,L2_11,lb2_0,lb2_1,
                    B0r[sl],B1r[sl]);
            }
        }
        #pragma unroll
        for(int sl=0; sl<4; sl++){
            int j = gtid + sl*NT;
            v2f Q0={qd[sl].x,qd[sl].z}, Q1={qd[sl].y,qd[sl].w};
            v2f P0={pd[sl].x,pd[sl].z}, P1={pd[sl].y,pd[sl].w};
            v2f u0 = f2_00*Q0 + f2_01*Q1 + fb2_0;
            v2f u1 = f2_10*Q0 + f2_11*Q1 + fb2_1;
            v2f h0 = tanh2(u0), h1 = tanh2(u1);
            v2f s0 = 1.0f - h0*h0, s1 = 1.0f - h1*h1;
            v2f a0 = f1_00*P0 + f1_10*P1;
            v2f a1 = f1_01*P0 + f1_11*P1;
            v2f w0 = a0*s0, w1 = a1*s1;
            v2f dp0 = c*(LR*B0r[sl] - (f2_00*w0 + f2_10*w1));
            v2f dp1 = c*(LR*B1r[sl] - (f2_01*w0 + f2_11*w1));
            op[j] = make_float4(dp0.x, dp1.x, dp0.y, dp1.y);
        }
    }else{
        for(int j = gtid; j < nv4; j += NT){
            float4 qq=q4[j], pp=p4[j];
            v2f Q0={qq.x,qq.z}, Q1={qq.y,qq.w};
            v2f P0={pp.x,pp.z}, P1={pp.y,pp.w};
            v2f Bs0={0.f,0.f}, Bs1={0.f,0.f};
            for(int k=0;k<NIT;k++){
                float4 P0v=pkS[k*5+0], P1v=pkS[k*5+1], P2v=pkS[k*5+2], P3v=pkS[k*5+3], P4v=pkS[k*5+4];
                bk_step2(Q0,Q1,P0,P1,
                    P0v.x,P0v.y,P0v.z,P0v.w, P1v.x,P1v.y,P1v.z,P1v.w, P2v.x,P2v.y,
                    P2v.z,P2v.w,P3v.x,P3v.y, P3v.z,P3v.w,P4v.x,P4v.y,P4v.z,P4v.w,
                    Bs0,Bs1);
            }
            v2f u0 = f2_00*Q0 + f2_01*Q1 + fb2_0;
            v2f u1 = f2_10*Q0 + f2_11*Q1 + fb2_1;
            v2f h0 = tanh2(u0), h1 = tanh2(u1);
            v2f s0 = 1.0f - h0*h0, s1 = 1.0f - h1*h1;
            v2f a0 = f1_00*P0 + f1_10*P1;
            v2f a1 = f1_01*P0 + f1_11*P1;
            v2f w0 = a0*s0, w1 = a1*s1;
            v2f dq0 = f1_00*h0 + f1_01*h1 + fb1_0;
            v2f dq1 = f1_10*h0 + f1_11*h1 + fb1_1;
            v2f dp0 = c*(LR*Bs0 - (f2_00*w0 + f2_10*w1));
            v2f dp1 = c*(LR*Bs1 - (f2_01*w0 + f2_11*w1));
            oq[j] = make_float4(dq0.x, dq1.x, dq0.y, dq1.y);
            op[j] = make_float4(dp0.x, dp1.x, dp0.y, dp1.y);
            float4 xx = x4[j];
            v2f X0={xx.x,xx.z}, X1={xx.y,xx.w};
            v2f xu0 = f2_00*X0 + f2_01*X1 + fb2_0;
            v2f xu1 = f2_10*X0 + f2_11*X1 + fb2_1;
            v2f xh0 = tanh2(xu0), xh1 = tanh2(xu1);
            v2f xd0 = f1_00*xh0 + f1_01*xh1 + fb1_0;
            v2f xd1 = f1_10*xh0 + f1_11*xh1 + fb1_1;
            ox[j] = make_float4(xd0.x, xd1.x, xd0.y, xd1.y);
        }
    }
}

extern "C" void kernel_launch(void* const* d_in, const int* in_sizes, int n_in,
                              void* d_out, int out_size, void* d_ws, size_t ws_size,
                              hipStream_t stream) {
    const float* inp = (const float*)d_in[1];
    const int K = in_sizes[1]/6;
    int nv4 = K >> 1;

    const float4* q4 = (const float4*)inp;
    const float4* p4 = (const float4*)(inp + 2*(size_t)K);
    const float4* x4 = (const float4*)(inp + 4*(size_t)K);

    float* part32 = (float*)d_ws;                  // [2][36][NB]
    unsigned* arr = (unsigned*)(part32 + 2*36*NB); // [NB]
    float c = 1.0f/(2.0f*(float)K);

    const float* t1i = (const float*)d_in[2];
    const float* b1i = (const float*)d_in[3];
    const float* t2i = (const float*)d_in[4];
    const float* b2i = (const float*)d_in[5];
    const float* invK = (const float*)d_in[6];
    const float* invKb= (const float*)d_in[7];

    float* out = (float*)d_out;
    float4* oq = (float4*)out;
    float4* op = (float4*)(out + 2*(size_t)K);
    float4* ox = (float4*)(out + 4*(size_t)K);

    // zero only the arrival epochs (1KB); partials are protocol-gated
    hipMemsetAsync(arr, 0, NB*sizeof(unsigned), stream);
    k_all<<<dim3(NB), dim3(TPB), 0, stream>>>(q4, p4, x4, nv4,
                                              t1i, b1i, t2i, b2i, invK, invKb,
                                              part32, arr, oq, op, ox, c);
}

// Round 11
// 255.221 us; speedup vs baseline: 1.3871x; 1.3871x over previous
//
#include <hip/hip_runtime.h>

// ShootingBlockMNModel1 — single fused kernel, regular launch (graph-safe).
// r9 structure (best: 192us kernel) + micro-bundle: 128B-aligned theta slots,
// tighter reader poll backoff, 12-thread parallel grad.
// Epoch-tagged u64 protocol: every shared datum is one atomic {f32,epoch}
// word — data is its own flag (no fences, no drains, no flag/payload split).
//   workers: 36 tagged partials; poll OWN 128B theta slot (detect==payload).
//   block 0 (dual role): worker duties + poll partial DATA coalesced,
//     grad (12-thread), broadcast tagged theta slots; then backfold + pk bcast.
//   final phase: oq/ox written BEFORE pk poll (overlaps block0's backfold),
//     then wave0 polls pk coalesced (7 u64/lane -> LDS), then B loop + op.
// Topology lesson (r2,r10): single-reducer + private-slot broadcast is the
// minimum-traffic sync; all-gather costs +4us/iter. r8 lesson: never exceed
// the proven 256-block 1-block/CU co-residency.
//
// ws (u64): part64[36*NB] ; tslot64[NB*16] (128B slots) ; pk64[400]

#define LR 0.25f
#define NIT 20
#define TPB 512
#define NB  256
#define TSTR 16                      // theta slot stride (u64) -> 128B aligned
#define GUARD (1<<20)

typedef float v2f __attribute__((ext_vector_type(2)));
typedef unsigned long long u64;

__device__ __forceinline__ u64 ld64_ag(const u64* p){
    return __hip_atomic_load(p, __ATOMIC_RELAXED, __HIP_MEMORY_SCOPE_AGENT);
}
__device__ __forceinline__ void st64_ep(u64* p, float v, unsigned ep){
    u64 x = ((u64)ep << 32) | (u64)__float_as_uint(v);
    __hip_atomic_store(p, x, __ATOMIC_RELAXED, __HIP_MEMORY_SCOPE_AGENT);
}
__device__ __forceinline__ unsigned ep_of(u64 x){ return (unsigned)(x >> 32); }
__device__ __forceinline__ float    val_of(u64 x){ return __uint_as_float((unsigned)(x & 0xffffffffull)); }

__device__ __forceinline__ v2f tanh2(v2f x){
    v2f e;
    e.x = __expf(x.x + x.x);
    e.y = __expf(x.y + x.y);
    v2f d = e + 1.0f;
    v2f r;
    r.x = __builtin_amdgcn_rcpf(d.x);
    r.y = __builtin_amdgcn_rcpf(d.y);
    return 1.0f - (r + r);
}

// wave64 sum via DPP on the VALU pipe; result valid in lane 63
#define DPP_ADD(x, ctrl) ((x) + __int_as_float(__builtin_amdgcn_update_dpp(0, __float_as_int(x), (ctrl), 0xF, 0xF, true)))
__device__ __forceinline__ float wave_sum64(float x){
    x = DPP_ADD(x, 0x111);   // row_shr:1
    x = DPP_ADD(x, 0x112);   // row_shr:2
    x = DPP_ADD(x, 0x114);   // row_shr:4
    x = DPP_ADD(x, 0x118);   // row_shr:8  -> lane 15+16r = row sum
    x = DPP_ADD(x, 0x142);   // row_bcast:15
    x = DPP_ADD(x, 0x143);   // row_bcast:31 -> lane 63 = total
    return x;
}

__device__ __forceinline__ void compute_grad(const float* s, const float* th,
                                             const float* ksym, const float* ksymb,
                                             float c, float* g){
    const float Ivec[4]={1.f,0.f,0.f,1.f};
    #pragma unroll
    for(int j=0;j<4;j++){
        float kv=0.f;
        #pragma unroll
        for(int m=0;m<4;m++) kv += ksym[j*4+m]*th[m];
        g[j] = kv - c*s[j];
    }
    #pragma unroll
    for(int i2=0;i2<2;i2++)
        g[4+i2] = ksymb[i2*2+0]*th[4] + ksymb[i2*2+1]*th[5] - c*s[4+i2];
    #pragma unroll
    for(int j=0;j<4;j++){
        float kv=0.f;
        #pragma unroll
        for(int m=0;m<4;m++) kv += ksym[j*4+m]*(th[6+m]-Ivec[m]);
        g[6+j] = kv - c*s[6+j];
    }
    #pragma unroll
    for(int i2=0;i2<2;i2++)
        g[10+i2] = ksymb[i2*2+0]*th[10] + ksymb[i2*2+1]*th[11] - c*s[10+i2];
}

// packed accumulate: float4 = 2 samples in v2f lanes
__device__ __forceinline__ void accum_sample2(v2f Q0, v2f Q1, v2f P0, v2f P1,
    float t1_00,float t1_01,float t1_10,float t1_11,
    float t2_00,float t2_01,float t2_10,float t2_11,float b2_0,float b2_1,
    v2f (&acc)[36]){
    v2f u0 = t2_00*Q0 + t2_01*Q1 + b2_0;
    v2f u1 = t2_10*Q0 + t2_11*Q1 + b2_1;
    v2f h0 = tanh2(u0), h1 = tanh2(u1);
    v2f s0 = 1.0f - h0*h0, s1 = 1.0f - h1*h1;
    v2f a0 = t1_00*P0 + t1_10*P1;
    v2f a1 = t1_01*P0 + t1_11*P1;
    v2f w0 = a0*s0, w1 = a1*s1;
    v2f r0 = -2.0f*(a0*h0)*s0, r1 = -2.0f*(a1*h1)*s1;
    acc[0]+=P0*h0; acc[1]+=P0*h1; acc[2]+=P1*h0; acc[3]+=P1*h1;
    acc[4]+=P0;    acc[5]+=P1;
    acc[6]+=w0*Q0; acc[7]+=w0*Q1; acc[8]+=w1*Q0; acc[9]+=w1*Q1;
    acc[10]+=w0;   acc[11]+=w1;
    v2f ps00=P0*s0, ps01=P0*s1, ps10=P1*s0, ps11=P1*s1;
    acc[12]+=ps00*Q0; acc[13]+=ps00*Q1; acc[14]+=ps01*Q0; acc[15]+=ps01*Q1;
    acc[16]+=ps10*Q0; acc[17]+=ps10*Q1; acc[18]+=ps11*Q0; acc[19]+=ps11*Q1;
    acc[20]+=ps00; acc[21]+=ps01; acc[22]+=ps10; acc[23]+=ps11;
    v2f r0q0=r0*Q0, r1q0=r1*Q0;
    acc[24]+=r0q0*Q0; acc[25]+=r0q0*Q1; acc[26]+=r0*(Q1*Q1);
    acc[27]+=r1q0*Q0; acc[28]+=r1q0*Q1; acc[29]+=r1*(Q1*Q1);
    acc[30]+=r0q0; acc[31]+=r0*Q1; acc[32]+=r1q0; acc[33]+=r1*Q1;
    acc[34]+=r0; acc[35]+=r1;
}

__device__ __forceinline__ void bk_step2(v2f Q0, v2f Q1, v2f P0, v2f P1,
    float t1_00,float t1_01,float t1_10,float t1_11,
    float t2_00,float t2_01,float t2_10,float t2_11,float b2_0,float b2_1,
    float L1_00,float L1_01,float L1_10,float L1_11,
    float L2_00,float L2_01,float L2_10,float L2_11,float lb2_0,float lb2_1,
    v2f &B0, v2f &B1){
    v2f u0 = t2_00*Q0 + t2_01*Q1 + b2_0;
    v2f u1 = t2_10*Q0 + t2_11*Q1 + b2_1;
    v2f h0 = tanh2(u0), h1 = tanh2(u1);
    v2f s0 = 1.0f - h0*h0, s1 = 1.0f - h1*h1;
    v2f a0 = t1_00*P0 + t1_10*P1;
    v2f a1 = t1_01*P0 + t1_11*P1;
    v2f w0 = a0*s0, w1 = a1*s1;
    v2f r0 = -2.0f*(a0*h0)*s0, r1 = -2.0f*(a1*h1)*s1;
    v2f lp0 = L1_00*P0 + L1_10*P1;
    v2f lp1 = L1_01*P0 + L1_11*P1;
    v2f z0 = L2_00*Q0 + L2_01*Q1 + lb2_0;
    v2f z1 = L2_10*Q0 + L2_11*Q1 + lb2_1;
    v2f m0 = lp0*s0 + r0*z0;
    v2f m1 = lp1*s1 + r1*z1;
    B0 += t2_00*m0 + t2_10*m1 + L2_00*w0 + L2_10*w1;
    B1 += t2_01*m0 + t2_11*m1 + L2_01*w0 + L2_11*w1;
}

__global__ __launch_bounds__(TPB, 2) void k_all(
    const float4* __restrict__ q4, const float4* __restrict__ p4,
    const float4* __restrict__ x4, int nv4,
    const float* __restrict__ t1i, const float* __restrict__ b1i,
    const float* __restrict__ t2i, const float* __restrict__ b2i,
    const float* __restrict__ invK, const float* __restrict__ invKb,
    u64* __restrict__ part64,            // [36][NB] tagged partials
    u64* __restrict__ tslot64,           // [NB][TSTR] tagged theta slots (128B)
    u64* __restrict__ pk64,              // [400] tagged pk broadcast
    float4* __restrict__ oq, float4* __restrict__ op, float4* __restrict__ ox,
    float c)
{
    const int tid  = threadIdx.x;
    const int bid  = blockIdx.x;
    const int NT   = gridDim.x * TPB;
    const int gtid = bid*TPB + tid;
    const int wave = tid >> 6, lane = tid & 63;

    __shared__ float ths[12];                  // current theta (ends as theta20)
    __shared__ float thetaAll[(NIT+1)*12];     // block0 only
    __shared__ float sAll[(NIT+1)*36];         // block0 only
    __shared__ float red[TPB/64][36];
    __shared__ float ks[16], ksb[4];
    __shared__ float4 pkS[NIT*5];              // packed theta_k + lam_{k+1}
    float* pkSf = (float*)pkS;

    if(tid < 16) ks[tid]  = 0.5f*(invK[tid]  + invK[(tid&3)*4 + (tid>>2)]);
    if(tid < 4)  ksb[tid] = 0.5f*(invKb[tid] + invKb[(tid&1)*2 + (tid>>1)]);
    if(tid < 12){
        float v = (tid<4)? t1i[tid] : (tid<6)? b1i[tid-4]
                : (tid<10)? t2i[tid-6] : b2i[tid-10];
        ths[tid] = v;
        thetaAll[tid] = v;
    }
    __syncthreads();

    // Pin this thread's samples in registers for the whole kernel.
    const bool fast = (nv4 == 4*NT);
    float4 qd[4], pd[4];
    if(fast){
        #pragma unroll
        for(int sl=0; sl<4; sl++){ qd[sl]=q4[gtid + sl*NT]; pd[sl]=p4[gtid + sl*NT]; }
    }

    for(int k=0; k<=NIT; k++){
        const float t1_00=ths[0], t1_01=ths[1], t1_10=ths[2], t1_11=ths[3];
        const float t2_00=ths[6], t2_01=ths[7], t2_10=ths[8], t2_11=ths[9];
        const float b2_0=ths[10], b2_1=ths[11];

        v2f acc[36];
        #pragma unroll
        for(int j=0;j<36;j++) acc[j] = (v2f){0.f, 0.f};

        if(fast){
            #pragma unroll
            for(int sl=0; sl<4; sl++){
                v2f Q0={qd[sl].x,qd[sl].z}, Q1={qd[sl].y,qd[sl].w};
                v2f P0={pd[sl].x,pd[sl].z}, P1={pd[sl].y,pd[sl].w};
                accum_sample2(Q0,Q1,P0,P1,
                    t1_00,t1_01,t1_10,t1_11,t2_00,t2_01,t2_10,t2_11,b2_0,b2_1,acc);
            }
        }else{
            for(int j = gtid; j < nv4; j += NT){
                float4 qq = q4[j], pp = p4[j];
                v2f Q0={qq.x,qq.z}, Q1={qq.y,qq.w};
                v2f P0={pp.x,pp.z}, P1={pp.y,pp.w};
                accum_sample2(Q0,Q1,P0,P1,
                    t1_00,t1_01,t1_10,t1_11,t2_00,t2_01,t2_10,t2_11,b2_0,b2_1,acc);
            }
        }

        // wave reduction (VALU pipe) -> block partials -> tagged u64 stores
        float wres[36];
        #pragma unroll
        for(int j=0;j<36;j++) wres[j] = wave_sum64(acc[j].x + acc[j].y);
        if(lane == 63){
            #pragma unroll
            for(int j=0;j<36;j++) red[wave][j] = wres[j];
        }
        __syncthreads();
        if(tid < 36){
            float sum = 0.f;
            #pragma unroll
            for(int w=0; w<TPB/64; w++) sum += red[w][tid];
            st64_ep(part64 + tid*NB + bid, sum, (unsigned)(k+1));  // no fence needed
        }

        if(bid == 0){
            // poll the partial DATA itself: rows {w, w+8, w+16, w+24}(+w+32 if w<4),
            // cols {lane, lane+64, lane+128, lane+192} — coalesced u64 loads.
            const unsigned tgt = (unsigned)(k+1);
            const int r4i = (wave<4)? (wave+32) : (wave+24);   // dummy repeat if wave>=4
            const u64* R0 = part64 + (size_t)(wave     )*NB;
            const u64* R1 = part64 + (size_t)(wave +  8)*NB;
            const u64* R2 = part64 + (size_t)(wave + 16)*NB;
            const u64* R3 = part64 + (size_t)(wave + 24)*NB;
            const u64* R4 = part64 + (size_t)(r4i      )*NB;
            u64 a0,a1,a2,a3, b0,b1,b2,b3, c0,c1,c2,c3, d0,d1,d2,d3, e0,e1,e2,e3;
            int guard = 0;
            for(;;){
                a0=ld64_ag(R0+lane); a1=ld64_ag(R0+lane+64); a2=ld64_ag(R0+lane+128); a3=ld64_ag(R0+lane+192);
                b0=ld64_ag(R1+lane); b1=ld64_ag(R1+lane+64); b2=ld64_ag(R1+lane+128); b3=ld64_ag(R1+lane+192);
                c0=ld64_ag(R2+lane); c1=ld64_ag(R2+lane+64); c2=ld64_ag(R2+lane+128); c3=ld64_ag(R2+lane+192);
                d0=ld64_ag(R3+lane); d1=ld64_ag(R3+lane+64); d2=ld64_ag(R3+lane+128); d3=ld64_ag(R3+lane+192);
                e0=ld64_ag(R4+lane); e1=ld64_ag(R4+lane+64); e2=ld64_ag(R4+lane+128); e3=ld64_ag(R4+lane+192);
                bool ok = ep_of(a0)>=tgt && ep_of(a1)>=tgt && ep_of(a2)>=tgt && ep_of(a3)>=tgt
                       && ep_of(b0)>=tgt && ep_of(b1)>=tgt && ep_of(b2)>=tgt && ep_of(b3)>=tgt
                       && ep_of(c0)>=tgt && ep_of(c1)>=tgt && ep_of(c2)>=tgt && ep_of(c3)>=tgt
                       && ep_of(d0)>=tgt && ep_of(d1)>=tgt && ep_of(d2)>=tgt && ep_of(d3)>=tgt
                       && ep_of(e0)>=tgt && ep_of(e1)>=tgt && ep_of(e2)>=tgt && ep_of(e3)>=tgt;
                if(__all(ok)) break;
                __builtin_amdgcn_s_sleep(1);
                if(++guard > GUARD) break;   // watchdog: wrong-answer, never hang
            }
            float s0 = wave_sum64(val_of(a0)+val_of(a1)+val_of(a2)+val_of(a3));
            float s1 = wave_sum64(val_of(b0)+val_of(b1)+val_of(b2)+val_of(b3));
            float s2 = wave_sum64(val_of(c0)+val_of(c1)+val_of(c2)+val_of(c3));
            float s3 = wave_sum64(val_of(d0)+val_of(d1)+val_of(d2)+val_of(d3));
            float s4 = wave_sum64(val_of(e0)+val_of(e1)+val_of(e2)+val_of(e3));
            if(lane == 63){
                sAll[k*36 + wave]      = s0;
                sAll[k*36 + wave + 8]  = s1;
                sAll[k*36 + wave + 16] = s2;
                sAll[k*36 + wave + 24] = s3;
                if(wave < 4) sAll[k*36 + wave + 32] = s4;
            }
            __syncthreads();
            // 12-thread parallel grad -> theta_{k+1}
            if(k < NIT){
                if(tid < 12){
                    const float* th = thetaAll + k*12;
                    const float* s  = sAll + k*36;
                    float g;
                    if(tid < 4){
                        float kv=0.f;
                        #pragma unroll
                        for(int m=0;m<4;m++) kv += ks[tid*4+m]*th[m];
                        g = kv - c*s[tid];
                    }else if(tid < 6){
                        int i2 = tid-4;
                        g = ksb[i2*2+0]*th[4] + ksb[i2*2+1]*th[5] - c*s[tid];
                    }else if(tid < 10){
                        int j = tid-6;
                        float kv=0.f;
                        #pragma unroll
                        for(int m=0;m<4;m++){
                            float Iv = (m==0 || m==3) ? 1.f : 0.f;
                            kv += ks[j*4+m]*(th[6+m]-Iv);
                        }
                        g = kv - c*s[tid];
                    }else{
                        int i2 = tid-10;
                        g = ksb[i2*2+0]*th[10] + ksb[i2*2+1]*th[11] - c*s[tid];
                    }
                    float t = th[tid] - LR*g;
                    ths[tid] = t;
                    thetaAll[(k+1)*12+tid] = t;
                }
                __syncthreads();
                // 256 slots x 12 tagged u64 (stride TSTR), coalesced; data==flag
                for(int f = tid; f < NB*12; f += TPB)
                    st64_ep(tslot64 + (f/12)*TSTR + (f%12), ths[f % 12], (unsigned)(k+1));
            }
        }else if(k < NIT){
            // readers: poll OWN 128B slot; detect == payload (same load)
            if(wave == 0){
                const unsigned tgt = (unsigned)(k+1);
                const u64* sp = tslot64 + bid*TSTR;
                const int idx = (lane < 12)? lane : 0;
                u64 v; int guard = 0;
                for(;;){
                    v = ld64_ag(sp + idx);
                    bool ok = (lane < 12)? (ep_of(v) >= tgt) : true;
                    if(__all(ok)) break;
                    __builtin_amdgcn_s_sleep(1);     // private line: light traffic
                    if(++guard > GUARD) break;       // watchdog
                }
                if(lane < 12) ths[lane] = val_of(v);
            }
            __syncthreads();
        }
    }

    // ---- backfold (block 0 only), then one tagged pk broadcast ----
    if(bid == 0){
        if(tid == 0){
            float lv[12];
            compute_grad(sAll + NIT*36, thetaAll + NIT*12, ks, ksb, c, lv);
            for(int k=NIT-1;k>=0;k--){
                const float* s = sAll + k*36;
                const float* T = thetaAll + k*12;
                float* P = (float*)&pkS[k*5];
                P[0]=T[0]; P[1]=T[1]; P[2]=T[2]; P[3]=T[3];
                P[4]=T[6]; P[5]=T[7]; P[6]=T[8]; P[7]=T[9];
                P[8]=T[10]; P[9]=T[11];
                P[10]=lv[0]; P[11]=lv[1]; P[12]=lv[2]; P[13]=lv[3];
                P[14]=lv[6]; P[15]=lv[7]; P[16]=lv[8]; P[17]=lv[9];
                P[18]=lv[10]; P[19]=lv[11];
                float H[12];
                for(int a=0;a<2;a++)for(int b=0;b<2;b++){
                    int j=a*2+b;
                    float data = s[12+a*4+b*2+0]*lv[6+b*2+0]
                               + s[12+a*4+b*2+1]*lv[6+b*2+1]
                               + s[20+a*2+b]*lv[10+b];
                    float kv=0.f;
                    for(int m=0;m<4;m++) kv += ks[j*4+m]*lv[m];
                    H[j]=kv - c*data;
                }
                H[4] = ksb[0]*lv[4] + ksb[1]*lv[5];
                H[5] = ksb[2]*lv[4] + ksb[3]*lv[5];
                for(int cc=0;cc<2;cc++)for(int d=0;d<2;d++){
                    int j=cc*2+d;
                    float term1 = lv[0+cc]*s[12+0*4+cc*2+d] + lv[2+cc]*s[12+1*4+cc*2+d];
                    float term2 = lv[6+cc*2+0]*s[24+cc*3+(0+d)] + lv[6+cc*2+1]*s[24+cc*3+(1+d)];
                    float term3 = lv[10+cc]*s[30+cc*2+d];
                    float kv=0.f;
                    for(int m=0;m<4;m++) kv += ks[j*4+m]*lv[6+m];
                    H[6+j]=kv - c*(term1+term2+term3);
                }
                for(int cc=0;cc<2;cc++){
                    float z1 = lv[0+cc]*s[20+0*2+cc] + lv[2+cc]*s[20+1*2+cc];
                    float z2 = lv[6+cc*2+0]*s[30+cc*2+0] + lv[6+cc*2+1]*s[30+cc*2+1];
                    float z3 = lv[10+cc]*s[34+cc];
                    float kv = ksb[cc*2+0]*lv[10] + ksb[cc*2+1]*lv[11];
                    H[10+cc]=kv - c*(z1+z2+z3);
                }
                for(int j=0;j<12;j++) lv[j] -= LR*H[j];
            }
        }
        __syncthreads();
        if(tid < NIT*20) st64_ep(pk64 + tid, pkSf[tid], (unsigned)(NIT+1));
    }

    // ---- final phase: ths == theta row 20; q/p still in registers ----
    const float f1_00=ths[0], f1_01=ths[1], f1_10=ths[2], f1_11=ths[3];
    const float fb1_0=ths[4], fb1_1=ths[5];
    const float f2_00=ths[6], f2_01=ths[7], f2_10=ths[8], f2_11=ths[9];
    const float fb2_0=ths[10], fb2_1=ths[11];

    if(fast){
        // 1) oq + ox now — overlaps block0's backfold + pk broadcast
        #pragma unroll
        for(int sl=0; sl<4; sl++){
            int j = gtid + sl*NT;
            v2f Q0={qd[sl].x,qd[sl].z}, Q1={qd[sl].y,qd[sl].w};
            v2f u0 = f2_00*Q0 + f2_01*Q1 + fb2_0;
            v2f u1 = f2_10*Q0 + f2_11*Q1 + fb2_1;
            v2f h0 = tanh2(u0), h1 = tanh2(u1);
            v2f dq0 = f1_00*h0 + f1_01*h1 + fb1_0;
            v2f dq1 = f1_10*h0 + f1_11*h1 + fb1_1;
            oq[j] = make_float4(dq0.x, dq1.x, dq0.y, dq1.y);
            float4 xx = x4[j];
            v2f X0={xx.x,xx.z}, X1={xx.y,xx.w};
            v2f xu0 = f2_00*X0 + f2_01*X1 + fb2_0;
            v2f xu1 = f2_10*X0 + f2_11*X1 + fb2_1;
            v2f xh0 = tanh2(xu0), xh1 = tanh2(xu1);
            v2f xd0 = f1_00*xh0 + f1_01*xh1 + fb1_0;
            v2f xd1 = f1_10*xh0 + f1_11*xh1 + fb1_1;
            ox[j] = make_float4(xd0.x, xd1.x, xd0.y, xd1.y);
        }
        // 2) non-block0: wave0 polls pk coalesced (7 u64/lane); payload -> LDS
        if(bid != 0){
            if(wave == 0){
                const unsigned tgt = (unsigned)(NIT+1);
                u64 v[7]; int guard = 0;
                for(;;){
                    bool ok = true;
                    #pragma unroll
                    for(int i=0;i<7;i++){
                        int idx = lane + i*64;
                        if(idx < NIT*20){
                            v[i] = ld64_ag(pk64 + idx);
                            ok = ok && (ep_of(v[i]) >= tgt);
                        }
                    }
                    if(__all(ok)) break;
                    __builtin_amdgcn_s_sleep(4);
                    if(++guard > GUARD) break;   // watchdog
                }
                #pragma unroll
                for(int i=0;i<7;i++){
                    int idx = lane + i*64;
                    if(idx < NIT*20) pkSf[idx] = val_of(v[i]);
                }
            }
            __syncthreads();
        }
        // 3) backward accumulation + op
        v2f B0r[4],B1r[4];
        #pragma unroll
        for(int sl=0; sl<4; sl++){ B0r[sl]=(v2f){0.f,0.f}; B1r[sl]=(v2f){0.f,0.f}; }
        for(int k=0;k<NIT;k++){
            float4 P0=pkS[k*5+0], P1=pkS[k*5+1], P2=pkS[k*5+2], P3=pkS[k*5+3], P4v=pkS[k*5+4];
            float t1_00=P0.x,t1_01=P0.y,t1_10=P0.z,t1_11=P0.w;
            float t2_00=P1.x,t2_01=P1.y,t2_10=P1.z,t2_11=P1.w;
            float b2_0=P2.x,b2_1=P2.y;
            float L1_00=P2.z,L1_01=P2.w,L1_10=P3.x,L1_11=P3.y;
            float L2_00=P3.z,L2_01=P3.w,L2_10=P4v.x,L2_11=P4v.y,lb2_0=P4v.z,lb2_1=P4v.w;
            #pragma unroll
            for(int sl=0; sl<4; sl++){
                v2f Q0={qd[sl].x,qd[sl].z}, Q1={qd[sl].y,qd[sl].w};
                v2f P0s={pd[sl].x,pd[sl].z}, P1s={pd[sl].y,pd[sl].w};
                bk_step2(Q0,Q1,P0s,P1s,
                    t1_00,t1_01,t1_10,t1_11,t2_00,t2_01,t2_10,t2_11,b2_0,b2_1,
                    L1_00,L1_01,L1_10,L1_11,L2_00,L2_01,L2_10,L2_11,lb2_0,lb2_1,
                    B0r[sl],B1r[sl]);
            }
        }
        #pragma unroll
        for(int sl=0; sl<4; sl++){
            int j = gtid + sl*NT;
            v2f Q0={qd[sl].x,qd[sl].z}, Q1={qd[sl].y,qd[sl].w};
            v2f P0={pd[sl].x,pd[sl].z}, P1={pd[sl].y,pd[sl].w};
            v2f u0 = f2_00*Q0 + f2_01*Q1 + fb2_0;
            v2f u1 = f2_10*Q0 + f2_11*Q1 + fb2_1;
            v2f h0 = tanh2(u0), h1 = tanh2(u1);
            v2f s0 = 1.0f - h0*h0, s1 = 1.0f - h1*h1;
            v2f a0 = f1_00*P0 + f1_10*P1;
            v2f a1 = f1_01*P0 + f1_11*P1;
            v2f w0 = a0*s0, w1 = a1*s1;
            v2f dp0 = c*(LR*B0r[sl] - (f2_00*w0 + f2_10*w1));
            v2f dp1 = c*(LR*B1r[sl] - (f2_01*w0 + f2_11*w1));
            op[j] = make_float4(dp0.x, dp1.x, dp0.y, dp1.y);
        }
    }else{
        // fallback: oq/ox pass, then poll pk, then op pass
        for(int j = gtid; j < nv4; j += NT){
            float4 qq=q4[j];
            v2f Q0={qq.x,qq.z}, Q1={qq.y,qq.w};
            v2f u0 = f2_00*Q0 + f2_01*Q1 + fb2_0;
            v2f u1 = f2_10*Q0 + f2_11*Q1 + fb2_1;
            v2f h0 = tanh2(u0), h1 = tanh2(u1);
            v2f dq0 = f1_00*h0 + f1_01*h1 + fb1_0;
            v2f dq1 = f1_10*h0 + f1_11*h1 + fb1_1;
            oq[j] = make_float4(dq0.x, dq1.x, dq0.y, dq1.y);
            float4 xx = x4[j];
            v2f X0={xx.x,xx.z}, X1={xx.y,xx.w};
            v2f xu0 = f2_00*X0 + f2_01*X1 + fb2_0;
            v2f xu1 = f2_10*X0 + f2_11*X1 + fb2_1;
            v2f xh0 = tanh2(xu0), xh1 = tanh2(xu1);
            v2f xd0 = f1_00*xh0 + f1_01*xh1 + fb1_0;
            v2f xd1 = f1_10*xh0 + f1_11*xh1 + fb1_1;
            ox[j] = make_float4(xd0.x, xd1.x, xd0.y, xd1.y);
        }
        if(bid != 0){
            if(wave == 0){
                const unsigned tgt = (unsigned)(NIT+1);
                u64 v[7]; int guard = 0;
                for(;;){
                    bool ok = true;
                    #pragma unroll
                    for(int i=0;i<7;i++){
                        int idx = lane + i*64;
                        if(idx < NIT*20){
                            v[i] = ld64_ag(pk64 + idx);
                            ok = ok && (ep_of(v[i]) >= tgt);
                        }
                    }
                    if(__all(ok)) break;
                    __builtin_amdgcn_s_sleep(4);
                    if(++guard > GUARD) break;   // watchdog
                }
                #pragma unroll
                for(int i=0;i<7;i++){
                    int idx = lane + i*64;
                    if(idx < NIT*20) pkSf[idx] = val_of(v[i]);
                }
            }
            __syncthreads();
        }
        for(int j = gtid; j < nv4; j += NT){
            float4 qq=q4[j], pp=p4[j];
            v2f Q0={qq.x,qq.z}, Q1={qq.y,qq.w};
            v2f P0={pp.x,pp.z}, P1={pp.y,pp.w};
            v2f Bs0={0.f,0.f}, Bs1={0.f,0.f};
            for(int k=0;k<NIT;k++){
                float4 P0v=pkS[k*5+0], P1v=pkS[k*5+1], P2v=pkS[k*5+2], P3v=pkS[k*5+3], P4v=pkS[k*5+4];
                bk_step2(Q0,Q1,P0,P1,
                    P0v.x,P0v.y,P0v.z,P0v.w, P1v.x,P1v.y,P1v.z,P1v.w, P2v.x,P2v.y,
                    P2v.z,P2v.w,P3v.x,P3v.y, P3v.z,P3v.w,P4v.x,P4v.y,P4v.z,P4v.w,
                    Bs0,Bs1);
            }
            v2f u0 = f2_00*Q0 + f2_01*Q1 + fb2_0;
            v2f u1 = f2_10*Q0 + f2_11*Q1 + fb2_1;
            v2f h0 = tanh2(u0), h1 = tanh2(u1);
            v2f s0 = 1.0f - h0*h0, s1 = 1.0f - h1*h1;
            v2f a0 = f1_00*P0 + f1_10*P1;
            v2f a1 = f1_01*P0 + f1_11*P1;
            v2f w0 = a0*s0, w1 = a1*s1;
            v2f dp0 = c*(LR*Bs0 - (f2_00*w0 + f2_10*w1));
            v2f dp1 = c*(LR*Bs1 - (f2_01*w0 + f2_11*w1));
            op[j] = make_float4(dp0.x, dp1.x, dp0.y, dp1.y);
        }
    }
}

extern "C" void kernel_launch(void* const* d_in, const int* in_sizes, int n_in,
                              void* d_out, int out_size, void* d_ws, size_t ws_size,
                              hipStream_t stream) {
    const float* inp = (const float*)d_in[1];
    const int K = in_sizes[1]/6;
    int nv4 = K >> 1;

    const float4* q4 = (const float4*)inp;
    const float4* p4 = (const float4*)(inp + 2*(size_t)K);
    const float4* x4 = (const float4*)(inp + 4*(size_t)K);

    u64* part64  = (u64*)d_ws;                 // [36*NB]
    u64* tslot64 = part64 + 36*NB;             // [NB*TSTR]
    u64* pk64    = tslot64 + NB*TSTR;          // [400]
    float c = 1.0f/(2.0f*(float)K);

    const float* t1i = (const float*)d_in[2];
    const float* b1i = (const float*)d_in[3];
    const float* t2i = (const float*)d_in[4];
    const float* b2i = (const float*)d_in[5];
    const float* invK = (const float*)d_in[6];
    const float* invKb= (const float*)d_in[7];

    float* out = (float*)d_out;
    float4* oq = (float4*)out;
    float4* op = (float4*)(out + 2*(size_t)K);
    float4* ox = (float4*)(out + 4*(size_t)K);

    // zero all epoch-bearing words (epochs restart at 0 every launch)
    size_t zb = (size_t)(36*NB + NB*TSTR + 400)*sizeof(u64);
    hipMemsetAsync(d_ws, 0, zb, stream);
    k_all<<<dim3(NB), dim3(TPB), 0, stream>>>(q4, p4, x4, nv4,
                                              t1i, b1i, t2i, b2i, invK, invKb,
                                              part64, tslot64, pk64, oq, op, ox, c);
}